// Round 6
// baseline (1626.715 us; speedup 1.0000x reference)
//
#include <hip/hip_runtime.h>

#define NG 16
#define NC 4
#define BPB 8      // batch items per block
#define TSTEPS 8

__device__ __forceinline__ void fma8(float w, const float4& s0, const float4& s1,
                                     float4& a0, float4& a1) {
    a0.x = fmaf(w, s0.x, a0.x);
    a0.y = fmaf(w, s0.y, a0.y);
    a0.z = fmaf(w, s0.z, a0.z);
    a0.w = fmaf(w, s0.w, a0.w);
    a1.x = fmaf(w, s1.x, a1.x);
    a1.y = fmaf(w, s1.y, a1.y);
    a1.z = fmaf(w, s1.z, a1.z);
    a1.w = fmaf(w, s1.w, a1.w);
}

__device__ __forceinline__ float4 lrelu4(float4 v) {
    float4 r;
    r.x = v.x > 0.f ? v.x : 0.1f * v.x;
    r.y = v.y > 0.f ? v.y : 0.1f * v.y;
    r.z = v.z > 0.f ? v.z : 0.1f * v.z;
    r.w = v.w > 0.f ? v.w : 0.1f * v.w;
    return r;
}

// Wt[(c*25+u*5+v)*256 + pix] : float4 over o, OOB (u,v) pre-zeroed.
// Original W: [y][x][o][c][u][v] (flat: pix*400 + o*100 + c*25 + u*5 + v)
__global__ void wt_transpose(const float* __restrict__ W, float4* __restrict__ Wt) {
    int t = blockIdx.x * 256 + threadIdx.x;   // 0..25599
    if (t >= 25600) return;
    int r = t >> 8;            // c*25 + u*5 + v
    int pix = t & 255;
    int c = r / 25, uv = r - c * 25, u = uv / 5, v = uv - u * 5;
    int y = pix >> 4, x = pix & 15;
    float4 w = make_float4(0.f, 0.f, 0.f, 0.f);
    if ((unsigned)(y + u - 2) < 16u && (unsigned)(x + v - 2) < 16u) {
        int base = pix * 400 + c * 25 + uv;
        w.x = W[base];
        w.y = W[base + 100];
        w.z = W[base + 200];
        w.w = W[base + 300];
    }
    Wt[r * 256 + pix] = w;
}

// Thread = pixel; owns all 4 output channels for 8 batch items.
// LDS: float4 smv[buf][c][y][x][2 slots], phys slot = logical ^ ((x>>2)&1).
// Weights: distance-1 register double-buffered stream. Two structural fixes
// vs R5 (which spilled 2.9 GB to scratch):
//  - amdgpu_waves_per_eu(2,2): LDS already caps us at 2 waves/EU, so give
//    the register allocator the full 256-VGPR budget (compiler chose 128
//    and spilled in R2-R5).
//  - sched_barrier(0) after every chunk: all 100 weight loads per step are
//    independent, and the pre-RA scheduler hoists them en masse, exploding
//    live range. Pin the pipeline at chunk granularity (<=10 loads in
//    flight); within a chunk the scheduler keeps full freedom.
__global__ __launch_bounds__(256)
__attribute__((amdgpu_waves_per_eu(2, 2)))
void reservoir_kernel(const float* __restrict__ X, const float4* __restrict__ Wt,
                      float* __restrict__ out, int batch) {
    __shared__ float4 smv[2 * NC * NG * NG * 2];   // 65536 B
    float* smf = reinterpret_cast<float*>(smv);

    const int tid = threadIdx.x;        // pixel index
    const int y = tid >> 4;
    const int x = tid & 15;
    const long itemBase = (long)blockIdx.x * BPB;

    const float4* Wp = Wt + tid;

    // ---- weight pipeline registers: 2 buffers x 5 float4, named ----
    float4 b0_0, b0_1, b0_2, b0_3, b0_4;
    float4 b1_0, b1_1, b1_2, b1_3, b1_4;

    // chunk k (= c*5+u) occupies Wp offsets k*1280 + v*256, v=0..4
#define LOADBUF(B, OFF) \
    B##_0 = Wp[(OFF)]; \
    B##_1 = Wp[(OFF) + 256]; \
    B##_2 = Wp[(OFF) + 512]; \
    B##_3 = Wp[(OFF) + 768]; \
    B##_4 = Wp[(OFF) + 1024];

    // prologue: chunk 0 -> buffer 0
    LOADBUF(b0, 0)

    // ---- init: X (first 784 of 1024 slots) -> LDS buf 0 (nontemporal) ----
    for (int b = 0; b < BPB; ++b) {
        long item = itemBase + b;
        const float* xr = X + item * 784;
        const int g = b >> 2, j = b & 3;
        #pragma unroll
        for (int kk = 0; kk < 4; ++kk) {
            int idx = tid + kk * 256;
            float v = 0.f;
            if (idx < 784 && item < batch) v = __builtin_nontemporal_load(&xr[idx]);
            int c = idx >> 8, rem = idx & 255, yy = rem >> 4, xx = rem & 15;
            int phys = g ^ ((xx >> 2) & 1);
            smf[(((c * NG + yy) * NG + xx) << 3) + phys * 4 + j] = v;
        }
    }

    int ybf[5], xbf[5];
    #pragma unroll
    for (int u = 0; u < 5; ++u) {
        int yy = y + u - 2;
        yy = yy < 0 ? 0 : (yy > 15 ? 15 : yy);
        ybf[u] = yy * (NG * 2);
    }
    #pragma unroll
    for (int v = 0; v < 5; ++v) {
        int xv = x + v - 2;
        xv = xv < 0 ? 0 : (xv > 15 ? 15 : xv);
        xbf[v] = xv * 2 + ((xv >> 2) & 1);
    }
    const int swx = (x >> 2) & 1;

    __syncthreads();

#define FMA_V(WV, V) { \
    const int i0 = sbase + xbf[V]; \
    const float4 s0 = smv[i0]; \
    const float4 s1 = smv[i0 ^ 1]; \
    fma8(WV.x, s0, s1, a00, a01); \
    fma8(WV.y, s0, s1, a10, a11); \
    fma8(WV.z, s0, s1, a20, a21); \
    fma8(WV.w, s0, s1, a30, a31); }

#define FMA5(B) FMA_V(B##_0, 0) FMA_V(B##_1, 1) FMA_V(B##_2, 2) FMA_V(B##_3, 3) FMA_V(B##_4, 4)

    // consume b0 (even chunk), prefetch next chunk into b1 — and vice versa.
    // sched_barrier(0) pins chunk boundaries (no cross-chunk load hoisting).
#define CH_A(C, U, POFF) \
    LOADBUF(b1, POFF) \
    { const int sbase = rbase + (C) * 512 + ybf[U]; FMA5(b0) } \
    __builtin_amdgcn_sched_barrier(0);
#define CH_B(C, U, POFF) \
    LOADBUF(b0, POFF) \
    { const int sbase = rbase + (C) * 512 + ybf[U]; FMA5(b1) } \
    __builtin_amdgcn_sched_barrier(0);

    #pragma unroll 1
    for (int t = 0; t < TSTEPS; ++t) {
        const int rbase = (t & 1) << 11;   // 2048 float4 per state buffer
        float4 a00 = {0,0,0,0}, a01 = {0,0,0,0};
        float4 a10 = {0,0,0,0}, a11 = {0,0,0,0};
        float4 a20 = {0,0,0,0}, a21 = {0,0,0,0};
        float4 a30 = {0,0,0,0}, a31 = {0,0,0,0};

        CH_A(0, 0, 1280)   // chunk 0, prefetch 1
        CH_B(0, 1, 2560)   // chunk 1, prefetch 2
        CH_A(0, 2, 3840)
        CH_B(0, 3, 5120)
        CH_A(0, 4, 6400)
        CH_B(1, 0, 7680)
        CH_A(1, 1, 8960)
        CH_B(1, 2, 10240)
        CH_A(1, 3, 11520)
        CH_B(1, 4, 12800)
        CH_A(2, 0, 14080)
        CH_B(2, 1, 15360)
        CH_A(2, 2, 16640)
        CH_B(2, 3, 17920)
        CH_A(2, 4, 19200)
        CH_B(3, 0, 20480)
        CH_A(3, 1, 21760)
        CH_B(3, 2, 23040)
        CH_A(3, 3, 24320)
        CH_B(3, 4, 0)      // chunk 19, prefetch chunk 0 for next step

        a00 = lrelu4(a00); a01 = lrelu4(a01);
        a10 = lrelu4(a10); a11 = lrelu4(a11);
        a20 = lrelu4(a20); a21 = lrelu4(a21);
        a30 = lrelu4(a30); a31 = lrelu4(a31);

        if (t < TSTEPS - 1) {
            const int wbase = rbase ^ 2048;
            const int pa = (y * NG + x) * 2;
            int c0 = wbase + 0 * 512 + pa;
            smv[c0 + swx] = a00; smv[c0 + (swx ^ 1)] = a01;
            int c1 = wbase + 1 * 512 + pa;
            smv[c1 + swx] = a10; smv[c1 + (swx ^ 1)] = a11;
            int c2 = wbase + 2 * 512 + pa;
            smv[c2 + swx] = a20; smv[c2 + (swx ^ 1)] = a21;
            int c3 = wbase + 3 * 512 + pa;
            smv[c3 + swx] = a30; smv[c3 + (swx ^ 1)] = a31;
            __syncthreads();
        } else {
            float4 p0, p1;
            p0.x = (a00.x + a10.x + a20.x + a30.x) * 0.25f;
            p0.y = (a00.y + a10.y + a20.y + a30.y) * 0.25f;
            p0.z = (a00.z + a10.z + a20.z + a30.z) * 0.25f;
            p0.w = (a00.w + a10.w + a20.w + a30.w) * 0.25f;
            p1.x = (a01.x + a11.x + a21.x + a31.x) * 0.25f;
            p1.y = (a01.y + a11.y + a21.y + a31.y) * 0.25f;
            p1.z = (a01.z + a11.z + a21.z + a31.z) * 0.25f;
            p1.w = (a01.w + a11.w + a21.w + a31.w) * 0.25f;
            long ob = itemBase * 256 + tid;
            if (itemBase + 0 < batch) __builtin_nontemporal_store(p0.x, &out[ob + 0 * 256]);
            if (itemBase + 1 < batch) __builtin_nontemporal_store(p0.y, &out[ob + 1 * 256]);
            if (itemBase + 2 < batch) __builtin_nontemporal_store(p0.z, &out[ob + 2 * 256]);
            if (itemBase + 3 < batch) __builtin_nontemporal_store(p0.w, &out[ob + 3 * 256]);
            if (itemBase + 4 < batch) __builtin_nontemporal_store(p1.x, &out[ob + 4 * 256]);
            if (itemBase + 5 < batch) __builtin_nontemporal_store(p1.y, &out[ob + 5 * 256]);
            if (itemBase + 6 < batch) __builtin_nontemporal_store(p1.z, &out[ob + 6 * 256]);
            if (itemBase + 7 < batch) __builtin_nontemporal_store(p1.w, &out[ob + 7 * 256]);
        }
    }
}

extern "C" void kernel_launch(void* const* d_in, const int* in_sizes, int n_in,
                              void* d_out, int out_size, void* d_ws, size_t ws_size,
                              hipStream_t stream) {
    const float* X = (const float*)d_in[0];
    const float* W = (const float*)d_in[1];
    float* out = (float*)d_out;
    const int batch = in_sizes[0] / 784;            // 8192
    const int blocks = (batch + BPB - 1) / BPB;     // 1024

    wt_transpose<<<100, 256, 0, stream>>>(W, (float4*)d_ws);
    reservoir_kernel<<<blocks, 256, 0, stream>>>(
        X, (const float4*)d_ws, out, batch);
}

// Round 7
// 257.427 us; speedup vs baseline: 6.3191x; 6.3191x over previous
//
#include <hip/hip_runtime.h>

#define NG 16
#define NC 4
#define BPB 8      // batch items per block
#define TSTEPS 8
#define PITCH 34   // float4 per (c,y) row: 16 x * 2 slots + 2 pad
#define CROW (NG * PITCH)   // 544 float4 per channel

__device__ __forceinline__ void fma8(float w, const float4& s0, const float4& s1,
                                     float4& a0, float4& a1) {
    a0.x = fmaf(w, s0.x, a0.x);
    a0.y = fmaf(w, s0.y, a0.y);
    a0.z = fmaf(w, s0.z, a0.z);
    a0.w = fmaf(w, s0.w, a0.w);
    a1.x = fmaf(w, s1.x, a1.x);
    a1.y = fmaf(w, s1.y, a1.y);
    a1.z = fmaf(w, s1.z, a1.z);
    a1.w = fmaf(w, s1.w, a1.w);
}

__device__ __forceinline__ float4 lrelu4(float4 v) {
    float4 r;
    r.x = v.x > 0.f ? v.x : 0.1f * v.x;
    r.y = v.y > 0.f ? v.y : 0.1f * v.y;
    r.z = v.z > 0.f ? v.z : 0.1f * v.z;
    r.w = v.w > 0.f ? v.w : 0.1f * v.w;
    return r;
}

// Wt[(c*25+u*5+v)*256 + pix] : float4 over o, OOB (u,v) pre-zeroed.
// Original W: [y][x][o][c][u][v] (flat: pix*400 + o*100 + c*25 + u*5 + v)
__global__ void wt_transpose(const float* __restrict__ W, float4* __restrict__ Wt) {
    int t = blockIdx.x * 256 + threadIdx.x;   // 0..25599
    if (t >= 25600) return;
    int r = t >> 8;            // c*25 + u*5 + v
    int pix = t & 255;
    int c = r / 25, uv = r - c * 25, u = uv / 5, v = uv - u * 5;
    int y = pix >> 4, x = pix & 15;
    float4 w = make_float4(0.f, 0.f, 0.f, 0.f);
    if ((unsigned)(y + u - 2) < 16u && (unsigned)(x + v - 2) < 16u) {
        int base = pix * 400 + c * 25 + uv;
        w.x = W[base];
        w.y = W[base + 100];
        w.z = W[base + 200];
        w.w = W[base + 300];
    }
    Wt[r * 256 + pix] = w;
}

// Thread = pixel; owns all 4 output channels for 8 batch items.
// SINGLE-buffered state LDS (2 barriers/step), pitch-34 rows + slot swizzle
// (conflict-free b128), 34816 B -> 4 blocks/CU = 4 waves/SIMD.
// Weights: distance-1 register double-buffer (2 x 5 float4 = 40 VGPR) inside
// a RUNTIME g-loop (g += 2; 10 static chunks/body, phase-invariant) — the
// runtime loop fences scheduler load-hoisting (R4-proven); fully-unrolled
// bodies spilled 3 GB to scratch in R3/R5/R6.
__global__ __launch_bounds__(256, 4)
void reservoir_kernel(const float* __restrict__ X, const float4* __restrict__ Wt,
                      float* __restrict__ out, int batch) {
    __shared__ float4 smv[NC * CROW];   // 34816 B
    float* smf = reinterpret_cast<float*>(smv);

    const int tid = threadIdx.x;        // pixel index
    const int y = tid >> 4;
    const int x = tid & 15;
    const long itemBase = (long)blockIdx.x * BPB;

    const float4* Wp = Wt + tid;

    // ---- weight pipeline registers: 2 buffers x 5 float4, named ----
    float4 b0_0, b0_1, b0_2, b0_3, b0_4;
    float4 b1_0, b1_1, b1_2, b1_3, b1_4;

#define LOADBUF(B, OFF) \
    B##_0 = Wp[(OFF)]; \
    B##_1 = Wp[(OFF) + 256]; \
    B##_2 = Wp[(OFF) + 512]; \
    B##_3 = Wp[(OFF) + 768]; \
    B##_4 = Wp[(OFF) + 1024];

    // prologue: chunk 0 -> buffer 0
    LOADBUF(b0, 0)

    // ---- init: X (first 784 of 1024 slots) -> LDS (nontemporal) ----
    for (int b = 0; b < BPB; ++b) {
        long item = itemBase + b;
        const float* xr = X + item * 784;
        const int g = b >> 2, j = b & 3;
        #pragma unroll
        for (int kk = 0; kk < 4; ++kk) {
            int idx = tid + kk * 256;
            float v = 0.f;
            if (idx < 784 && item < batch) v = __builtin_nontemporal_load(&xr[idx]);
            int c = idx >> 8, rem = idx & 255, yy = rem >> 4, xx = rem & 15;
            int phys = g ^ ((xx >> 2) & 1);
            smf[((c * NG + yy) * PITCH + xx * 2 + phys) * 4 + j] = v;
        }
    }

    int ybf[5], xbf[5];
    #pragma unroll
    for (int u = 0; u < 5; ++u) {
        int yy = y + u - 2;
        yy = yy < 0 ? 0 : (yy > 15 ? 15 : yy);
        ybf[u] = yy * PITCH;
    }
    #pragma unroll
    for (int v = 0; v < 5; ++v) {
        int xv = x + v - 2;
        xv = xv < 0 ? 0 : (xv > 15 ? 15 : xv);
        xbf[v] = xv * 2 + ((xv >> 2) & 1);    // phys slot-0 offset
    }
    const int swx = (x >> 2) & 1;
    const int pa = y * PITCH + x * 2;

    __syncthreads();

#define FMA_V(WV, V) { \
    const int i0 = sbase + xbf[V]; \
    const float4 s0 = smv[i0]; \
    const float4 s1 = smv[i0 ^ 1]; \
    fma8(WV.x, s0, s1, a00, a01); \
    fma8(WV.y, s0, s1, a10, a11); \
    fma8(WV.z, s0, s1, a20, a21); \
    fma8(WV.w, s0, s1, a30, a31); }

#define FMA5(B) FMA_V(B##_0, 0) FMA_V(B##_1, 1) FMA_V(B##_2, 2) FMA_V(B##_3, 3) FMA_V(B##_4, 4)

    // consume b0 (even chunk), prefetch next chunk into b1 — and vice versa
#define CH_A(CB, U, POFF) \
    LOADBUF(b1, POFF) \
    { const int sbase = (CB) + ybf[U]; FMA5(b0) }
#define CH_B(CB, U, POFF) \
    LOADBUF(b0, POFF) \
    { const int sbase = (CB) + ybf[U]; FMA5(b1) }

    #pragma unroll 1
    for (int t = 0; t < TSTEPS; ++t) {
        float4 a00 = {0,0,0,0}, a01 = {0,0,0,0};
        float4 a10 = {0,0,0,0}, a11 = {0,0,0,0};
        float4 a20 = {0,0,0,0}, a21 = {0,0,0,0};
        float4 a30 = {0,0,0,0}, a31 = {0,0,0,0};

        #pragma unroll 1
        for (int g = 0; g < 4; g += 2) {    // chunk k = c*5+u at Wp f4 off k*1280
            const int cb0 = g * CROW;       // c = g
            const int cb1 = cb0 + CROW;     // c = g+1
            const int wo = g * 6400;
            const int wlast = (g == 2) ? 0 : wo + 12800;  // wrap to chunk 0

            CH_A(cb0, 0, wo + 1280)
            CH_B(cb0, 1, wo + 2560)
            CH_A(cb0, 2, wo + 3840)
            CH_B(cb0, 3, wo + 5120)
            CH_A(cb0, 4, wo + 6400)
            CH_B(cb1, 0, wo + 7680)
            CH_A(cb1, 1, wo + 8960)
            CH_B(cb1, 2, wo + 10240)
            CH_A(cb1, 3, wo + 11520)
            CH_B(cb1, 4, wlast)
        }

        a00 = lrelu4(a00); a01 = lrelu4(a01);
        a10 = lrelu4(a10); a11 = lrelu4(a11);
        a20 = lrelu4(a20); a21 = lrelu4(a21);
        a30 = lrelu4(a30); a31 = lrelu4(a31);

        if (t < TSTEPS - 1) {
            __syncthreads();   // all reads of S[t] complete before overwrite
            int c0 = 0 * CROW + pa;
            smv[c0 + swx] = a00; smv[c0 + (swx ^ 1)] = a01;
            int c1 = 1 * CROW + pa;
            smv[c1 + swx] = a10; smv[c1 + (swx ^ 1)] = a11;
            int c2 = 2 * CROW + pa;
            smv[c2 + swx] = a20; smv[c2 + (swx ^ 1)] = a21;
            int c3 = 3 * CROW + pa;
            smv[c3 + swx] = a30; smv[c3 + (swx ^ 1)] = a31;
            __syncthreads();   // writes visible before next read phase
        } else {
            float4 p0, p1;
            p0.x = (a00.x + a10.x + a20.x + a30.x) * 0.25f;
            p0.y = (a00.y + a10.y + a20.y + a30.y) * 0.25f;
            p0.z = (a00.z + a10.z + a20.z + a30.z) * 0.25f;
            p0.w = (a00.w + a10.w + a20.w + a30.w) * 0.25f;
            p1.x = (a01.x + a11.x + a21.x + a31.x) * 0.25f;
            p1.y = (a01.y + a11.y + a21.y + a31.y) * 0.25f;
            p1.z = (a01.z + a11.z + a21.z + a31.z) * 0.25f;
            p1.w = (a01.w + a11.w + a21.w + a31.w) * 0.25f;
            long ob = itemBase * 256 + tid;
            if (itemBase + 0 < batch) __builtin_nontemporal_store(p0.x, &out[ob + 0 * 256]);
            if (itemBase + 1 < batch) __builtin_nontemporal_store(p0.y, &out[ob + 1 * 256]);
            if (itemBase + 2 < batch) __builtin_nontemporal_store(p0.z, &out[ob + 2 * 256]);
            if (itemBase + 3 < batch) __builtin_nontemporal_store(p0.w, &out[ob + 3 * 256]);
            if (itemBase + 4 < batch) __builtin_nontemporal_store(p1.x, &out[ob + 4 * 256]);
            if (itemBase + 5 < batch) __builtin_nontemporal_store(p1.y, &out[ob + 5 * 256]);
            if (itemBase + 6 < batch) __builtin_nontemporal_store(p1.z, &out[ob + 6 * 256]);
            if (itemBase + 7 < batch) __builtin_nontemporal_store(p1.w, &out[ob + 7 * 256]);
        }
    }
}

extern "C" void kernel_launch(void* const* d_in, const int* in_sizes, int n_in,
                              void* d_out, int out_size, void* d_ws, size_t ws_size,
                              hipStream_t stream) {
    const float* X = (const float*)d_in[0];
    const float* W = (const float*)d_in[1];
    float* out = (float*)d_out;
    const int batch = in_sizes[0] / 784;            // 8192
    const int blocks = (batch + BPB - 1) / BPB;     // 1024

    wt_transpose<<<100, 256, 0, stream>>>(W, (float4*)d_ws);
    reservoir_kernel<<<blocks, 256, 0, stream>>>(
        X, (const float4*)d_ws, out, batch);
}